// Round 3
// baseline (83.175 us; speedup 1.0000x reference)
//
#include <hip/hip_runtime.h>
#include <hip/hip_bf16.h>

#define TDIM 1024
#define KDIM 32

typedef short bf16x8 __attribute__((ext_vector_type(8)));
typedef float f32x4  __attribute__((ext_vector_type(4)));

__device__ __forceinline__ unsigned short f2bf(float x) {
    __hip_bfloat16 h = __float2bfloat16(x);
    return *reinterpret_cast<unsigned short*>(&h);
}

__device__ __forceinline__ int read_len(const int* __restrict__ lengths32, int b) {
    // int64 little-endian: int32 view at odd index 1 is high word of lengths[0] == 0.
    // int32: lengths[1] in [1,1024], never 0.  (verified in rounds 1-2)
    const bool is64 = (lengths32[1] == 0);
    int len = is64 ? lengths32[2 * b] : lengths32[b];
    return len < 1 ? 1 : (len > TDIM ? TDIM : len);
}

// ---------------- K1: per-(batch, chunk) 32x32 product matrix -------------
// P_chunk = prod_{t in [1+c*CHS, min(1+(c+1)CHS, len)) } E^T D_t
// bf16 col-major (addr = col*32+row), integer power-of-2 scale ledger.
// Rescale applied every 4 steps; ds_bpermute pipelined one step ahead so the
// serial chain is only C -> mul -> cvt -> MFMA.
template<int CHS, int NCH>
__global__ __launch_bounds__(64) void crf_chunk_kernel(
    const float* __restrict__ emissions,    // [B, T, K]
    const int*   __restrict__ lengths32,
    const float* __restrict__ transitions,  // [K, K]
    unsigned int* __restrict__ Pout,        // [B][NCH][1024] bf16 as 512 dwords
    int*          __restrict__ toteOut)     // [B][NCH]
{
    const int c    = blockIdx.x;
    const int b    = blockIdx.y;
    const int lane = threadIdx.x;
    const int n    = lane & 15;   // tile col / A row (local)
    const int g    = lane >> 4;   // lane group 0..3
    const int j32  = lane & 31;

    const int len    = read_len(lengths32, b);
    const int tstart = 1 + c * CHS;
    int count = len - tstart; if (count > CHS) count = CHS;
    if (count <= 0) return;                       // dead chunk

    // slot -> contraction-row map: rho(g,e) = e<4 ? 4g+e : 16+4g+(e-4)
    int rho[8];
#pragma unroll
    for (int e = 0; e < 8; ++e) rho[e] = (e < 4) ? (4 * g + e) : (16 + 4 * g + (e - 4));

    // Static A-frags: A_I elem e = E^T[16I+n][rho] = exp(trans[rho][16I+n])
    bf16x8 A0, A1;
#pragma unroll
    for (int e = 0; e < 8; ++e) {
        A0[e] = (short)f2bf(__expf(transitions[rho[e] * KDIM + n]));
        A1[e] = (short)f2bf(__expf(transitions[rho[e] * KDIM + 16 + n]));
    }

    int bpa[8];
#pragma unroll
    for (int e = 0; e < 8; ++e) bpa[e] = rho[e] * 4;

    // P = Identity in C-frags: tile(I,J) reg q: row=16I+4g+q, col=16J+n
    f32x4 C00, C01, C10, C11;
#pragma unroll
    for (int q = 0; q < 4; ++q) {
        float d = (4 * g + q == n) ? 1.0f : 0.0f;
        C00[q] = d; C11[q] = d; C01[q] = 0.0f; C10[q] = 0.0f;
    }

    const float* eptr = emissions + (size_t)b * TDIM * KDIM + j32;
    const f32x4 zero = {0.0f, 0.0f, 0.0f, 0.0f};

    // ---- software pipeline state ----
    float epf[8];                 // raw emissions for steps i..i+7
#pragma unroll
    for (int u = 0; u < 8; ++u) {
        int t = tstart + u; t = t > (TDIM - 1) ? (TDIM - 1) : t;
        epf[u] = eptr[t * KDIM];
    }
    float ev0 = __expf(epf[0]);
    float evd[8];                 // bpermuted exp(emis) for current step
#pragma unroll
    for (int e = 0; e < 8; ++e)
        evd[e] = __int_as_float(__builtin_amdgcn_ds_bpermute(bpa[e], __float_as_int(ev0)));

    float sf = 1.0f;              // pending power-of-2 rescale
    int pend = 0, tote = 0;

    // core of one step: consume evd, produce new C; fold scale if dofold
    auto BODY = [&](bool dofold, float evdN[8]) {
        if (dofold) {
#pragma unroll
            for (int e = 0; e < 8; ++e) evd[e] *= sf;
            tote += pend;
        }
        bf16x8 B0, B1;
#pragma unroll
        for (int q = 0; q < 4; ++q) {
            B0[q]     = (short)f2bf(C00[q] * evd[q]);
            B0[q + 4] = (short)f2bf(C10[q] * evd[q + 4]);
            B1[q]     = (short)f2bf(C01[q] * evd[q]);
            B1[q + 4] = (short)f2bf(C11[q] * evd[q + 4]);
        }
        C00 = __builtin_amdgcn_mfma_f32_16x16x32_bf16(A0, B0, zero, 0, 0, 0);
        C01 = __builtin_amdgcn_mfma_f32_16x16x32_bf16(A0, B1, zero, 0, 0, 0);
        C10 = __builtin_amdgcn_mfma_f32_16x16x32_bf16(A1, B0, zero, 0, 0, 0);
        C11 = __builtin_amdgcn_mfma_f32_16x16x32_bf16(A1, B1, zero, 0, 0, 0);
#pragma unroll
        for (int e = 0; e < 8; ++e) evd[e] = evdN[e];
    };
    auto RESCALE = [&]() {
        int bits = __builtin_amdgcn_readfirstlane(__float_as_int(C00[0]));
        pend = ((bits >> 23) & 255) - 127;
        sf = __uint_as_float((unsigned)(127 - pend) << 23);
    };

    int i = 0;
    for (; i + 8 <= count; i += 8) {
#pragma unroll
        for (int u = 0; u < 8; ++u) {
            // pipeline: prepare evd for step i+u+1 (independent of C chain)
            float evn = __expf(epf[(u + 1) & 7]);
            int tld = tstart + i + u + 8; tld = tld > (TDIM - 1) ? (TDIM - 1) : tld;
            epf[u] = eptr[tld * KDIM];
            float evdN[8];
#pragma unroll
            for (int e = 0; e < 8; ++e)
                evdN[e] = __int_as_float(__builtin_amdgcn_ds_bpermute(bpa[e], __float_as_int(evn)));
            BODY((u & 3) == 0, evdN);
            if (u == 3 || u == 7) RESCALE();
        }
    }
    // tail: < 8 steps, per-step rescale, fresh loads (rare: last alive chunk only)
    for (; i < count; ++i) {
        int tn = tstart + i + 1; tn = tn > (TDIM - 1) ? (TDIM - 1) : tn;
        float evn = __expf(eptr[tn * KDIM]);
        float evdN[8];
#pragma unroll
        for (int e = 0; e < 8; ++e)
            evdN[e] = __int_as_float(__builtin_amdgcn_ds_bpermute(bpa[e], __float_as_int(evn)));
        BODY(true, evdN);
        RESCALE();
    }

    // store bf16 col-major: dword idx = col*16 + row/2
    unsigned int* outP = Pout + ((size_t)b * NCH + c) * 512;
#pragma unroll
    for (int p = 0; p < 2; ++p) {
        int q = 2 * p;
        outP[n * 16        + (4 * g + q) / 2]       = (unsigned)f2bf(C00[q]) | ((unsigned)f2bf(C00[q + 1]) << 16);
        outP[(16 + n) * 16 + (4 * g + q) / 2]       = (unsigned)f2bf(C01[q]) | ((unsigned)f2bf(C01[q + 1]) << 16);
        outP[n * 16        + (16 + 4 * g + q) / 2]  = (unsigned)f2bf(C10[q]) | ((unsigned)f2bf(C10[q + 1]) << 16);
        outP[(16 + n) * 16 + (16 + 4 * g + q) / 2]  = (unsigned)f2bf(C11[q]) | ((unsigned)f2bf(C11[q + 1]) << 16);
    }
    if (lane == 0) toteOut[b * NCH + c] = tote;
}

// ---------------- K2: chain chunk matrices through alpha ------------------
template<int NCH, int CHS>
__global__ __launch_bounds__(64) void crf_combine_kernel(
    const float* __restrict__ emissions,
    const int*   __restrict__ lengths32,
    const float* __restrict__ head_t,
    const float* __restrict__ last_t,
    const unsigned short* __restrict__ Pbuf,  // [B][NCH][1024] bf16 col-major
    const int*   __restrict__ toteBuf,
    float*       __restrict__ out)
{
    __shared__ unsigned short Plds[NCH * 1024];
    const int b    = blockIdx.x;
    const int lane = threadIdx.x;
    const int j    = lane & 31;

    const int len = read_len(lengths32, b);
    int nAlive = (len - 1 + CHS - 1) / CHS;
    if (nAlive > NCH) nAlive = NCH;

    const uint4* src = (const uint4*)(Pbuf + (size_t)b * NCH * 1024);
    uint4* dst = (uint4*)Plds;
    for (int idx = lane; idx < nAlive * 128; idx += 64) dst[idx] = src[idx];
    __syncthreads();

    float alpha = __expf(head_t[j] + emissions[(size_t)b * TDIM * KDIM + j]);
    int tote = 0;

    for (int cix = 0; cix < nAlive; ++cix) {
        const unsigned short* P = Plds + cix * 1024;
        float a0 = 0.f, a1 = 0.f, a2 = 0.f, a3 = 0.f;
#pragma unroll
        for (int q = 0; q < 8; ++q) {
            int k0 = q * 4;
            float p0 = __uint_as_float((unsigned)P[(k0 + 0) * KDIM + j] << 16);
            float p1 = __uint_as_float((unsigned)P[(k0 + 1) * KDIM + j] << 16);
            float p2 = __uint_as_float((unsigned)P[(k0 + 2) * KDIM + j] << 16);
            float p3 = __uint_as_float((unsigned)P[(k0 + 3) * KDIM + j] << 16);
            a0 = fmaf(p0, __int_as_float(__builtin_amdgcn_readlane(__float_as_int(alpha), k0 + 0)), a0);
            a1 = fmaf(p1, __int_as_float(__builtin_amdgcn_readlane(__float_as_int(alpha), k0 + 1)), a1);
            a2 = fmaf(p2, __int_as_float(__builtin_amdgcn_readlane(__float_as_int(alpha), k0 + 2)), a2);
            a3 = fmaf(p3, __int_as_float(__builtin_amdgcn_readlane(__float_as_int(alpha), k0 + 3)), a3);
        }
        float acc = (a0 + a1) + (a2 + a3);
        int bits = __builtin_amdgcn_readfirstlane(__float_as_int(acc));
        int s = ((bits >> 23) & 255) - 127;
        alpha = acc * __uint_as_float((unsigned)(127 - s) << 23);
        tote += s + toteBuf[b * NCH + cix];
    }

    float p = alpha * __expf(last_t[j]);
#pragma unroll
    for (int m = 16; m >= 1; m >>= 1)
        p += __shfl_xor(p, m, 64);

    if (lane == 0)
        out[b] = __logf(p) + (float)tote * 0.69314718055994531f;
}

extern "C" void kernel_launch(void* const* d_in, const int* in_sizes, int n_in,
                              void* d_out, int out_size, void* d_ws, size_t ws_size,
                              hipStream_t stream)
{
    const float* emissions   = (const float*)d_in[0];
    const int*   lengths     = (const int*)d_in[1];
    const float* transitions = (const float*)d_in[2];
    const float* head_t      = (const float*)d_in[3];
    const float* last_t      = (const float*)d_in[4];
    float* out = (float*)d_out;
    const int B = out_size;  // 512

    unsigned int* Pbuf = (unsigned int*)d_ws;

    const size_t need16 = (size_t)B * 16 * 2048 + (size_t)B * 16 * 4;
    if (ws_size >= need16) {
        int* toteBf = (int*)((char*)d_ws + (size_t)B * 16 * 2048);
        dim3 g1(16, B);
        crf_chunk_kernel<64, 16><<<g1, 64, 0, stream>>>(emissions, lengths, transitions, Pbuf, toteBf);
        crf_combine_kernel<16, 64><<<B, 64, 0, stream>>>(emissions, lengths, head_t, last_t,
                                                         (const unsigned short*)Pbuf, toteBf, out);
    } else {
        int* toteBf = (int*)((char*)d_ws + (size_t)B * 8 * 2048);
        dim3 g1(8, B);
        crf_chunk_kernel<128, 8><<<g1, 64, 0, stream>>>(emissions, lengths, transitions, Pbuf, toteBf);
        crf_combine_kernel<8, 128><<<B, 64, 0, stream>>>(emissions, lengths, head_t, last_t,
                                                         (const unsigned short*)Pbuf, toteBf, out);
    }
}